// Round 17
// baseline (126.053 us; speedup 1.0000x reference)
//
#include <hip/hip_runtime.h>
#include <stdint.h>

using u16    = unsigned short;
using u32    = unsigned int;
using short8 = __attribute__((ext_vector_type(8))) short;
using s16x4  = __attribute__((ext_vector_type(4))) short;
using f32x4  = __attribute__((ext_vector_type(4))) float;
using f32x16 = __attribute__((ext_vector_type(16))) float;
using i32x4  = __attribute__((ext_vector_type(4))) int;

constexpr float LOG2E = 1.44269504088896340736f;

// ---- helpers ---------------------------------------------------------------

__device__ __forceinline__ u16 f2bf(float f) {
  uint32_t u = __builtin_bit_cast(uint32_t, f);
  return (u16)((u + 0x7fffu + ((u >> 16) & 1u)) >> 16);
}

__device__ __forceinline__ void gload16(const void* g, void* l) {
  __builtin_amdgcn_global_load_lds(
      (const __attribute__((address_space(1))) unsigned int*)g,
      (__attribute__((address_space(3))) unsigned int*)l, 16, 0, 0);
}

__device__ __forceinline__ u32 cvtpk_bf16(float lo, float hi) {
  u32 r;
  asm("v_cvt_pk_bf16_f32 %0, %1, %2" : "=v"(r) : "v"(lo), "v"(hi));
  return r;
}

__device__ __forceinline__ f32x16 zero16() {
  f32x16 z;
#pragma unroll
  for (int i = 0; i < 16; ++i) z[i] = 0.f;
  return z;
}

// 128-byte-row LDS tile, XOR-swizzled (GEMM staging path)
__device__ __forceinline__ short8 ldfrag(const u16* s, int row, int kbyte) {
  int phys = (row << 7) + (kbyte ^ ((row & 7) << 4));
  return *(const short8*)((const char*)s + phys);
}

// ---- prep: casts + LDS-tiled weight transposes + K-aug mask + mask flag ----
__global__ __launch_bounds__(256) void prep_kernel(
    const float4* __restrict__ qin, const float4* __restrict__ rin,
    const float* __restrict__ mask,
    const float* __restrict__ wq, const float* __restrict__ wk,
    const float* __restrict__ wv, const float* __restrict__ wo,
    u16* __restrict__ xq, u16* __restrict__ xr,
    u16* __restrict__ wqt, u16* __restrict__ wkt,
    u16* __restrict__ wvt, u16* __restrict__ wot,
    u16* __restrict__ kfr, int* __restrict__ mflag) {
  __shared__ float tlds[64][65];  // padded: conflict-free transpose
  const int gid = blockIdx.x * blockDim.x + threadIdx.x;
  const int stride = gridDim.x * blockDim.x;
  for (int i = gid; i < (2 * 4096 * 512) / 4; i += stride) {
    float4 a = qin[i], b = rin[i];
    s16x4 va = {(short)f2bf(a.x), (short)f2bf(a.y), (short)f2bf(a.z), (short)f2bf(a.w)};
    s16x4 vb = {(short)f2bf(b.x), (short)f2bf(b.y), (short)f2bf(b.z), (short)f2bf(b.w)};
    *(s16x4*)(xq + i * 4) = va;
    *(s16x4*)(xr + i * 4) = vb;
  }
  // tiled transposes: blocks 0..255 -> (weight w, 64x64 tile tr,tc), coalesced
  if (blockIdx.x < 256) {
    const int tid = threadIdx.x;
    const int w = blockIdx.x >> 6, tpos = blockIdx.x & 63;
    const int tr = tpos >> 3, tc = tpos & 7;
    const float* src = (w == 0) ? wq : (w == 1) ? wk : (w == 2) ? wv : wo;
    u16* dst = (w == 0) ? wqt : (w == 1) ? wkt : (w == 2) ? wvt : wot;
#pragma unroll
    for (int p = 0; p < 16; ++p) {
      int r = p * 4 + (tid >> 6), c = tid & 63;
      tlds[r][c] = src[(size_t)(tr * 64 + r) * 512 + tc * 64 + c];
    }
    __syncthreads();
#pragma unroll
    for (int p = 0; p < 16; ++p) {
      int c2 = p * 4 + (tid >> 6), r2 = tid & 63;
      dst[(size_t)(tc * 64 + c2) * 512 + tr * 64 + r2] = f2bf(tlds[r2][c2]);
    }
  }
  // augmented mask slot 4: value mt at (hh=0, j=0), zeros elsewhere.
  for (int i = gid; i < 16 * 4096; i += stride) {
    int head = i >> 12, key = i & 4095;
    int nn = head >> 3;
    float mv = mask[nn * 4096 + key];
    float mt = mv * (-1.0e9f * LOG2E);
    int tile = key >> 5, lqk = key & 31;
    u16* base = kfr + (((size_t)(head * 128 + tile)) * 5 + 4) * 512;
    u16* p0 = base + (size_t)lqk * 8;         // hh=0
    u16* p1 = base + (size_t)(32 + lqk) * 8;  // hh=1
    p0[0] = f2bf(mt);
#pragma unroll
    for (int j = 1; j < 8; ++j) p0[j] = 0;
#pragma unroll
    for (int j = 0; j < 8; ++j) p1[j] = 0;
    unsigned long long any = __ballot(mv != 0.0f);
    if ((threadIdx.x & 63) == 0 && any != 0ULL) atomicOr(mflag, 1);
  }
}

// ---- shared 128x128 tile GEMM core (C = A * Bt^T), K multiple of 64 --------
__device__ __forceinline__ void gemm_core(const u16* __restrict__ A, const u16* __restrict__ Bt,
                                          int K, u16* As, u16* Bs, int tm0, int tn0,
                                          f32x4 acc[4][4]) {
  const int tid = threadIdx.x;
  const int wv = tid >> 6, ln = tid & 63;
  const int lr = ln & 15, hi = ln >> 4;
  const int wr = wv >> 1, wc = wv & 1;
  const size_t rowbytes = (size_t)K * 2;
  for (int k0 = 0; k0 < K; k0 += 64) {
    __syncthreads();
    const char* Ab = (const char*)A + (size_t)tm0 * rowbytes + (size_t)k0 * 2;
    const char* Bb = (const char*)Bt + (size_t)tn0 * rowbytes + (size_t)k0 * 2;
#pragma unroll
    for (int c = 0; c < 4; ++c) {
      int lin = wv * 4096 + c * 1024 + ln * 16;
      int row = lin >> 7;
      int cb = (lin & 127) ^ ((row & 7) << 4);  // pre-swizzled global source
      gload16(Ab + (size_t)row * rowbytes + cb, (char*)As + wv * 4096 + c * 1024);
      gload16(Bb + (size_t)row * rowbytes + cb, (char*)Bs + wv * 4096 + c * 1024);
    }
    __syncthreads();
#pragma unroll
    for (int ks = 0; ks < 2; ++ks) {
      short8 af[4], bf[4];
#pragma unroll
      for (int m = 0; m < 4; ++m) af[m] = ldfrag(As, wr * 64 + m * 16 + lr, ks * 64 + hi * 16);
#pragma unroll
      for (int n = 0; n < 4; ++n) bf[n] = ldfrag(Bs, wc * 64 + n * 16 + lr, ks * 64 + hi * 16);
#pragma unroll
      for (int m = 0; m < 4; ++m)
#pragma unroll
        for (int n = 0; n < 4; ++n)
          acc[m][n] = __builtin_amdgcn_mfma_f32_16x16x32_bf16(af[m], bf[n], acc[m][n], 0, 0, 0);
    }
  }
}

// ---- QKV projection: z=0 -> q; z=1 -> K frag-major; z=2 -> V^T frag-major --
__global__ __launch_bounds__(256) void qkv_gemm(
    const u16* __restrict__ xq, const u16* __restrict__ xr,
    const u16* __restrict__ wqt, const u16* __restrict__ wkt, const u16* __restrict__ wvt,
    u16* __restrict__ qo, u16* __restrict__ kfr, u16* __restrict__ vfr) {
  __shared__ u16 As[128 * 64];
  __shared__ u16 Bs[128 * 64];
  const int z = blockIdx.z;
  const u16* A  = (z == 0) ? xq : xr;
  const u16* Bt = (z == 0) ? wqt : (z == 1) ? wkt : wvt;
  const int tm0 = blockIdx.x * 128, tn0 = blockIdx.y * 128;
  f32x4 acc[4][4];
#pragma unroll
  for (int m = 0; m < 4; ++m)
#pragma unroll
    for (int n = 0; n < 4; ++n) { f32x4 zz = {0.f, 0.f, 0.f, 0.f}; acc[m][n] = zz; }
  gemm_core(A, Bt, 512, As, Bs, tm0, tn0, acc);

  const int tid = threadIdx.x, wv = tid >> 6, ln = tid & 63, lr = ln & 15, hi = ln >> 4;
  const int wr = wv >> 1, wc = wv & 1;
  const float scale = (z == 0) ? 0.125f * LOG2E : 1.0f;  // fold log2e for exp2 softmax
#pragma unroll
  for (int m = 0; m < 4; ++m) {
#pragma unroll
    for (int n = 0; n < 4; ++n) {
#pragma unroll
      for (int r = 0; r < 4; ++r) {
        int rg = tm0 + wr * 64 + m * 16 + hi * 4 + r;  // global row in [0,8192)
        int cg = tn0 + wc * 64 + n * 16 + lr;          // global col in [0,512)
        int nb = rg >> 12, t = rg & 4095;
        int h = cg >> 6, s = cg & 63;
        int head = nb * 8 + h;
        u16 b = f2bf(acc[m][n][r] * scale);
        if (z == 0) {
          qo[((size_t)head * 4096 + t) * 64 + s] = b;
        } else if (z == 1) {
          int tile = t >> 5, lqk = t & 31;
          int ks = s >> 4, hh = (s >> 3) & 1, j = s & 7;
          kfr[((((size_t)(head * 128 + tile)) * 5 + ks) * 64 + hh * 32 + lqk) * 8 + j] = b;
        } else {
          // V^T frag-major: key from t, s-lane from s (swapped-PV A-operand)
          int tile = t >> 5, key5 = t & 31;
          int c = key5 >> 4, w = key5 & 15;
          int hh2 = (w >> 2) & 1;
          int j2 = (w & 3) + ((w >> 3) << 2);
          int st = s >> 5, lqs = s & 31;
          vfr[((((size_t)(head * 128 + tile)) * 4 + c * 2 + st) * 64 + hh2 * 32 + lqs) * 8 + j2] = b;
        }
      }
    }
  }
}

// ---- flash attention v17: rotated software pipeline (T15, zero extra regs) -
// body(t): QK_b(t) -> sm_a(t) -> PV_a(t) -> QK_a(t+1) -> sm_b(t) -> PV_b(t)
// grid 256 blocks (xcd-affine, 2 heads/XCD), 512 thr:
// qt = wv&3 (64 q-rows), kg = wv>>2 (2048 keys = 64 tiles of KBLK=32).
__global__ __launch_bounds__(512, 2) void attn17_kernel(
    const u16* __restrict__ q, const char* __restrict__ kfr, const char* __restrict__ vfr,
    u16* __restrict__ ctx, const int* __restrict__ mflag) {
  __shared__ __align__(16) char smem[4 * 32 * 65 * 4];  // 33280B, aliased below
  __shared__ float cl[4][64];
  float (*cmbraw)[32][64] = (float(*)[32][64])smem;   // KSPLIT partial pass
  float (*cmb2)[32][65]   = (float(*)[32][65])smem;   // padded transpose pass
  const int id = blockIdx.x;
  const int xcd = id & 7, slot = id >> 3;
  const int head = xcd * 2 + (slot >> 4);  // 2 heads per XCD
  const int qb = slot & 15;
  const int n = head >> 3, h = head & 7;
  const int tid = threadIdx.x, wv = tid >> 6, ln = tid & 63;
  const int lq = ln & 31, hi = ln >> 5, hi4 = hi * 4;
  const int qt = wv & 3, kg = wv >> 2;
  const int q0 = qb * 256 + qt * 64;
  const bool aug = (*mflag != 0);  // uniform: mask has nonzero entries?

  // Q fragments for two q-sets (rows q0+lq and q0+32+lq); [4]=aug unit col
  short8 qfa[5], qfb[5];
  {
    const char* qp = (const char*)(q + (size_t)head * 4096 * 64) + (size_t)(q0 + lq) * 128 + hi * 16;
#pragma unroll
    for (int ks = 0; ks < 4; ++ks) {
      qfa[ks] = *(const short8*)(qp + ks * 32);
      qfb[ks] = *(const short8*)(qp + 32 * 128 + ks * 32);
    }
    short8 z = {0, 0, 0, 0, 0, 0, 0, 0};
    if (hi == 0) z[0] = (short)0x3F80;  // bf16 1.0 at s=64 (mask aug)
    qfa[4] = z;
    qfb[4] = z;
  }

  // frag-major bases: every load is base + ln*16 (fully coalesced)
  const char* kp = kfr + (size_t)head * 655360 + (size_t)(kg * 64) * 5120 + ln * 16;
  const char* vp = vfr + (size_t)head * 524288 + (size_t)(kg * 64) * 4096 + ln * 16;

  // prologue: kA <- tile 0; Sa(0) = QK_a(tile 0)
  short8 kA[5];
#pragma unroll
  for (int s = 0; s < 4; ++s) kA[s] = *(const short8*)(kp + s * 1024);
  if (aug) kA[4] = *(const short8*)(kp + 4 * 1024);

  f32x16 Sa = zero16();
  __builtin_amdgcn_s_setprio(1);
#pragma unroll
  for (int ks = 0; ks < 4; ++ks)
    Sa = __builtin_amdgcn_mfma_f32_32x32x16_bf16(kA[ks], qfa[ks], Sa, 0, 0, 0);
  if (aug) Sa = __builtin_amdgcn_mfma_f32_32x32x16_bf16(kA[4], qfa[4], Sa, 0, 0, 0);
  __builtin_amdgcn_s_setprio(0);

  f32x16 cacc0a = zero16(), cacc1a = zero16();  // s 0..31 / 32..63 (regs), q lanes
  f32x16 cacc0b = zero16(), cacc1b = zero16();
  f32x16 la = zero16(), lb = zero16();  // deferred row-sum accumulators

  for (int it = 0; it < 64; ++it) {
    // V^T frags for current tile
    short8 vt[4];
#pragma unroll
    for (int s = 0; s < 4; ++s) vt[s] = *(const short8*)(vp + s * 1024);
    vp += 4096;

    // ---- step 1: QK_b(it) with kA (tile it)
    f32x16 Sb = zero16();
    __builtin_amdgcn_s_setprio(1);
#pragma unroll
    for (int ks = 0; ks < 4; ++ks)
      Sb = __builtin_amdgcn_mfma_f32_32x32x16_bf16(kA[ks], qfb[ks], Sb, 0, 0, 0);
    if (aug) Sb = __builtin_amdgcn_mfma_f32_32x32x16_bf16(kA[4], qfb[4], Sb, 0, 0, 0);
    __builtin_amdgcn_s_setprio(0);

    // ---- prefetch kN <- tile it+1 (used at step 4; hidden under sm_a/PV_a)
    short8 kN[5];
    kp += 5120;
#pragma unroll
    for (int s = 0; s < 4; ++s) kN[s] = *(const short8*)(kp + s * 1024);
    if (aug) kN[4] = *(const short8*)(kp + 4 * 1024);

    // ---- step 2: softmax_a(it) — Sa's QK issued last iter (fully drained)
    float pa_[16];
#pragma unroll
    for (int r = 0; r < 16; ++r) { pa_[r] = __builtin_amdgcn_exp2f(Sa[r]); la[r] += pa_[r]; }
    short8 pA0, pA1;
    {
      i32x4 f0 = {(int)cvtpk_bf16(pa_[0], pa_[1]), (int)cvtpk_bf16(pa_[2], pa_[3]),
                  (int)cvtpk_bf16(pa_[4], pa_[5]), (int)cvtpk_bf16(pa_[6], pa_[7])};
      i32x4 f1 = {(int)cvtpk_bf16(pa_[8], pa_[9]), (int)cvtpk_bf16(pa_[10], pa_[11]),
                  (int)cvtpk_bf16(pa_[12], pa_[13]), (int)cvtpk_bf16(pa_[14], pa_[15])};
      pA0 = __builtin_bit_cast(short8, f0);
      pA1 = __builtin_bit_cast(short8, f1);
    }

    // ---- step 3: PV_a(it)
    __builtin_amdgcn_s_setprio(1);
    cacc0a = __builtin_amdgcn_mfma_f32_32x32x16_bf16(vt[0], pA0, cacc0a, 0, 0, 0);
    cacc1a = __builtin_amdgcn_mfma_f32_32x32x16_bf16(vt[1], pA0, cacc1a, 0, 0, 0);
    cacc0a = __builtin_amdgcn_mfma_f32_32x32x16_bf16(vt[2], pA1, cacc0a, 0, 0, 0);
    cacc1a = __builtin_amdgcn_mfma_f32_32x32x16_bf16(vt[3], pA1, cacc1a, 0, 0, 0);
    __builtin_amdgcn_s_setprio(0);

    // ---- step 4: QK_a(it+1) with kN (skipped on last iter)
    f32x16 San = zero16();
    if (it < 63) {
      __builtin_amdgcn_s_setprio(1);
#pragma unroll
      for (int ks = 0; ks < 4; ++ks)
        San = __builtin_amdgcn_mfma_f32_32x32x16_bf16(kN[ks], qfa[ks], San, 0, 0, 0);
      if (aug) San = __builtin_amdgcn_mfma_f32_32x32x16_bf16(kN[4], qfa[4], San, 0, 0, 0);
      __builtin_amdgcn_s_setprio(0);
    }

    // ---- step 5: softmax_b(it) — Sb issued step 1, 8+ MFMA + VALU ago
    float pb_[16];
#pragma unroll
    for (int r = 0; r < 16; ++r) { pb_[r] = __builtin_amdgcn_exp2f(Sb[r]); lb[r] += pb_[r]; }
    short8 pB0, pB1;
    {
      i32x4 g0 = {(int)cvtpk_bf16(pb_[0], pb_[1]), (int)cvtpk_bf16(pb_[2], pb_[3]),
                  (int)cvtpk_bf16(pb_[4], pb_[5]), (int)cvtpk_bf16(pb_[6], pb_[7])};
      i32x4 g1 = {(int)cvtpk_bf16(pb_[8], pb_[9]), (int)cvtpk_bf16(pb_[10], pb_[11]),
                  (int)cvtpk_bf16(pb_[12], pb_[13]), (int)cvtpk_bf16(pb_[14], pb_[15])};
      pB0 = __builtin_bit_cast(short8, g0);
      pB1 = __builtin_bit_cast(short8, g1);
    }

    // ---- step 6: PV_b(it)
    __builtin_amdgcn_s_setprio(1);
    cacc0b = __builtin_amdgcn_mfma_f32_32x32x16_bf16(vt[0], pB0, cacc0b, 0, 0, 0);
    cacc1b = __builtin_amdgcn_mfma_f32_32x32x16_bf16(vt[1], pB0, cacc1b, 0, 0, 0);
    cacc0b = __builtin_amdgcn_mfma_f32_32x32x16_bf16(vt[2], pB1, cacc0b, 0, 0, 0);
    cacc1b = __builtin_amdgcn_mfma_f32_32x32x16_bf16(vt[3], pB1, cacc1b, 0, 0, 0);
    __builtin_amdgcn_s_setprio(0);

    Sa = San;
#pragma unroll
    for (int s = 0; s < 4; ++s) kA[s] = kN[s];
    if (aug) kA[4] = kN[4];
  }

  // ---- finalize deferred row-sums (per-lane q -> no bpermute needed)
  float lra, lrb;
  {
    float ta[16], tb[16];
#pragma unroll
    for (int r = 0; r < 16; ++r) { ta[r] = la[r]; tb[r] = lb[r]; }
#pragma unroll
    for (int d = 8; d > 0; d >>= 1)
#pragma unroll
      for (int r = 0; r < d; ++r) { ta[r] += ta[r + d]; tb[r] += tb[r + d]; }
    lra = ta[0] + __shfl_xor(ta[0], 32);
    lrb = tb[0] + __shfl_xor(tb[0], 32);
  }

  // ---- KSPLIT combine + normalize + LDS transpose + coalesced store -------
  auto epilogue = [&](f32x16& c0, f32x16& c1, float lr, int qofs) {
    if (kg == 1) {
#pragma unroll
      for (int r = 0; r < 16; ++r) {
        cmbraw[qt][r][ln] = c0[r];
        cmbraw[qt][r + 16][ln] = c1[r];
      }
      cl[qt][ln] = lr;
    }
    __syncthreads();
    if (kg == 0) {
#pragma unroll
      for (int r = 0; r < 16; ++r) {
        c0[r] += cmbraw[qt][r][ln];
        c1[r] += cmbraw[qt][r + 16][ln];
      }
      lr += cl[qt][ln];
    }
    __syncthreads();  // cmbraw dead; region becomes cmb2
    if (kg == 0) {
      float li = 1.0f / lr;
#pragma unroll
      for (int r = 0; r < 16; ++r) {
        int s0 = (r & 3) + ((r >> 2) << 3) + hi4;  // s within 32-half
        cmb2[qt][lq][s0] = c0[r] * li;
        cmb2[qt][lq][32 + s0] = c1[r] * li;
      }
    }
    __syncthreads();
    {
      u16* cpx = ctx + (size_t)(n * 4096 + qb * 256 + qt * 64 + qofs) * 512 + h * 64;
#pragma unroll
      for (int rr = 0; rr < 16; ++rr) {
        int qq = kg * 16 + rr;
        cpx[(size_t)qq * 512 + ln] = f2bf(cmb2[qt][qq][ln]);
      }
    }
    __syncthreads();  // before region is reused
  };
  epilogue(cacc0a, cacc1a, lra, 0);
  epilogue(cacc0b, cacc1b, lrb, 32);
}

// ---- output projection: 128x64 tiles (2 blocks/CU), out = ctx * WoT^T ------
__global__ __launch_bounds__(256) void out_gemm(
    const u16* __restrict__ ctx, const u16* __restrict__ wot, float* __restrict__ out) {
  __shared__ u16 As[128 * 64];  // 16KB
  __shared__ u16 Bs[64 * 64];   // 8KB
  const int tm0 = blockIdx.x * 128, tn0 = blockIdx.y * 64;
  const int tid = threadIdx.x, wv = tid >> 6, ln = tid & 63;
  const int lr = ln & 15, hi = ln >> 4;
  f32x4 acc[2][4];
#pragma unroll
  for (int m = 0; m < 2; ++m)
#pragma unroll
    for (int n = 0; n < 4; ++n) { f32x4 zz = {0.f, 0.f, 0.f, 0.f}; acc[m][n] = zz; }

  const size_t rowbytes = 1024;  // K=512 * 2B
  for (int k0 = 0; k0 < 512; k0 += 64) {
    __syncthreads();
    const char* Ab = (const char*)ctx + (size_t)tm0 * rowbytes + (size_t)k0 * 2;
    const char* Bb = (const char*)wot + (size_t)tn0 * rowbytes + (size_t)k0 * 2;
#pragma unroll
    for (int c = 0; c < 4; ++c) {
      int lin = wv * 4096 + c * 1024 + ln * 16;
      int row = lin >> 7;
      int cb = (lin & 127) ^ ((row & 7) << 4);
      gload16(Ab + (size_t)row * rowbytes + cb, (char*)As + wv * 4096 + c * 1024);
    }
#pragma unroll
    for (int c = 0; c < 2; ++c) {
      int lin = wv * 2048 + c * 1024 + ln * 16;
      int row = lin >> 7;
      int cb = (lin & 127) ^ ((row & 7) << 4);
      gload16(Bb + (size_t)row * rowbytes + cb, (char*)Bs + wv * 2048 + c * 1024);
    }
    __syncthreads();
#pragma unroll
    for (int ks = 0; ks < 2; ++ks) {
      short8 af[2], bf[4];
#pragma unroll
      for (int m = 0; m < 2; ++m) af[m] = ldfrag(As, wv * 32 + m * 16 + lr, ks * 64 + hi * 16);
#pragma unroll
      for (int n = 0; n < 4; ++n) bf[n] = ldfrag(Bs, n * 16 + lr, ks * 64 + hi * 16);
#pragma unroll
      for (int m = 0; m < 2; ++m)
#pragma unroll
        for (int n = 0; n < 4; ++n)
          acc[m][n] = __builtin_amdgcn_mfma_f32_16x16x32_bf16(af[m], bf[n], acc[m][n], 0, 0, 0);
    }
  }
#pragma unroll
  for (int m = 0; m < 2; ++m)
#pragma unroll
    for (int n = 0; n < 4; ++n)
#pragma unroll
      for (int r = 0; r < 4; ++r) {
        int rg = tm0 + wv * 32 + m * 16 + hi * 4 + r;
        int cg = tn0 + n * 16 + lr;
        out[(size_t)rg * 512 + cg] = acc[m][n][r];
      }
}

// ---- launch ----------------------------------------------------------------
extern "C" void kernel_launch(void* const* d_in, const int* in_sizes, int n_in,
                              void* d_out, int out_size, void* d_ws, size_t ws_size,
                              hipStream_t stream) {
  (void)in_sizes; (void)n_in; (void)out_size; (void)ws_size;
  const float* qin  = (const float*)d_in[0];
  const float* rin  = (const float*)d_in[1];
  const float* mask = (const float*)d_in[2];
  const float* wq   = (const float*)d_in[3];
  const float* wk   = (const float*)d_in[4];
  const float* wv   = (const float*)d_in[5];
  const float* wo   = (const float*)d_in[6];

  char* ws = (char*)d_ws;
  u16* xq   = (u16*)(ws + 0);         // [8192][512] bf16 (region reused by ctx)
  u16* ctx  = (u16*)(ws + 0);         // [8192][512] bf16 (written after xq dead)
  u16* xr   = (u16*)(ws + 8388608);   // [8192][512]
  u16* wqt  = (u16*)(ws + 16777216);  // [512][512] transposed
  u16* wkt  = (u16*)(ws + 17301504);
  u16* wvt  = (u16*)(ws + 17825792);
  u16* wot  = (u16*)(ws + 18350080);
  u16* qo   = (u16*)(ws + 18874368);  // [16][4096][64]
  u16* kfr  = (u16*)(ws + 27262976);  // frag-major K+mask: 16*128*5*64*8 u16 = 10.5MB
  u16* vfr  = (u16*)(ws + 37748736);  // frag-major V^T:    16*128*4*64*8 u16 = 8MB
  int* mflag = (int*)(ws + 46137344); // mask-nonzero flag

  hipMemsetAsync(mflag, 0, 4, stream);
  prep_kernel<<<2048, 256, 0, stream>>>((const float4*)qin, (const float4*)rin, mask,
                                        wq, wk, wv, wo, xq, xr, wqt, wkt, wvt, wot,
                                        kfr, mflag);
  qkv_gemm<<<dim3(64, 4, 3), 256, 0, stream>>>(xq, xr, wqt, wkt, wvt, qo, kfr, vfr);
  attn17_kernel<<<256, 512, 0, stream>>>(qo, (const char*)kfr, (const char*)vfr, ctx, mflag);
  out_gemm<<<dim3(64, 8), 256, 0, stream>>>(ctx, wot, (float*)d_out);
}

// Round 18
// 121.130 us; speedup vs baseline: 1.0406x; 1.0406x over previous
//
#include <hip/hip_runtime.h>
#include <stdint.h>

using u16    = unsigned short;
using u32    = unsigned int;
using short8 = __attribute__((ext_vector_type(8))) short;
using s16x4  = __attribute__((ext_vector_type(4))) short;
using f32x4  = __attribute__((ext_vector_type(4))) float;
using f32x16 = __attribute__((ext_vector_type(16))) float;
using i32x4  = __attribute__((ext_vector_type(4))) int;

constexpr float LOG2E = 1.44269504088896340736f;

// ---- helpers ---------------------------------------------------------------

__device__ __forceinline__ u16 f2bf(float f) {
  uint32_t u = __builtin_bit_cast(uint32_t, f);
  return (u16)((u + 0x7fffu + ((u >> 16) & 1u)) >> 16);
}

__device__ __forceinline__ void gload16(const void* g, void* l) {
  __builtin_amdgcn_global_load_lds(
      (const __attribute__((address_space(1))) unsigned int*)g,
      (__attribute__((address_space(3))) unsigned int*)l, 16, 0, 0);
}

__device__ __forceinline__ u32 cvtpk_bf16(float lo, float hi) {
  u32 r;
  asm("v_cvt_pk_bf16_f32 %0, %1, %2" : "=v"(r) : "v"(lo), "v"(hi));
  return r;
}

__device__ __forceinline__ f32x16 zero16() {
  f32x16 z;
#pragma unroll
  for (int i = 0; i < 16; ++i) z[i] = 0.f;
  return z;
}

// 128-byte-row LDS tile, XOR-swizzled (GEMM staging path)
__device__ __forceinline__ short8 ldfrag(const u16* s, int row, int kbyte) {
  int phys = (row << 7) + (kbyte ^ ((row & 7) << 4));
  return *(const short8*)((const char*)s + phys);
}

// ---- prep: casts + LDS-tiled weight transposes + K-aug mask + mask flag ----
__global__ __launch_bounds__(256) void prep_kernel(
    const float4* __restrict__ qin, const float4* __restrict__ rin,
    const float* __restrict__ mask,
    const float* __restrict__ wq, const float* __restrict__ wk,
    const float* __restrict__ wv, const float* __restrict__ wo,
    u16* __restrict__ xq, u16* __restrict__ xr,
    u16* __restrict__ wqt, u16* __restrict__ wkt,
    u16* __restrict__ wvt, u16* __restrict__ wot,
    u16* __restrict__ kfr, int* __restrict__ mflag) {
  __shared__ float tlds[64][65];  // padded: conflict-free transpose
  const int gid = blockIdx.x * blockDim.x + threadIdx.x;
  const int stride = gridDim.x * blockDim.x;
  for (int i = gid; i < (2 * 4096 * 512) / 4; i += stride) {
    float4 a = qin[i], b = rin[i];
    s16x4 va = {(short)f2bf(a.x), (short)f2bf(a.y), (short)f2bf(a.z), (short)f2bf(a.w)};
    s16x4 vb = {(short)f2bf(b.x), (short)f2bf(b.y), (short)f2bf(b.z), (short)f2bf(b.w)};
    *(s16x4*)(xq + i * 4) = va;
    *(s16x4*)(xr + i * 4) = vb;
  }
  // tiled transposes: blocks 0..255 -> (weight w, 64x64 tile tr,tc), coalesced
  if (blockIdx.x < 256) {
    const int tid = threadIdx.x;
    const int w = blockIdx.x >> 6, tpos = blockIdx.x & 63;
    const int tr = tpos >> 3, tc = tpos & 7;
    const float* src = (w == 0) ? wq : (w == 1) ? wk : (w == 2) ? wv : wo;
    u16* dst = (w == 0) ? wqt : (w == 1) ? wkt : (w == 2) ? wvt : wot;
#pragma unroll
    for (int p = 0; p < 16; ++p) {
      int r = p * 4 + (tid >> 6), c = tid & 63;
      tlds[r][c] = src[(size_t)(tr * 64 + r) * 512 + tc * 64 + c];
    }
    __syncthreads();
#pragma unroll
    for (int p = 0; p < 16; ++p) {
      int c2 = p * 4 + (tid >> 6), r2 = tid & 63;
      dst[(size_t)(tc * 64 + c2) * 512 + tr * 64 + r2] = f2bf(tlds[r2][c2]);
    }
  }
  // augmented mask slot 4: value mt at (hh=0, j=0), zeros elsewhere.
  for (int i = gid; i < 16 * 4096; i += stride) {
    int head = i >> 12, key = i & 4095;
    int nn = head >> 3;
    float mv = mask[nn * 4096 + key];
    float mt = mv * (-1.0e9f * LOG2E);
    int tile = key >> 5, lqk = key & 31;
    u16* base = kfr + (((size_t)(head * 128 + tile)) * 5 + 4) * 512;
    u16* p0 = base + (size_t)lqk * 8;         // hh=0
    u16* p1 = base + (size_t)(32 + lqk) * 8;  // hh=1
    p0[0] = f2bf(mt);
#pragma unroll
    for (int j = 1; j < 8; ++j) p0[j] = 0;
#pragma unroll
    for (int j = 0; j < 8; ++j) p1[j] = 0;
    unsigned long long any = __ballot(mv != 0.0f);
    if ((threadIdx.x & 63) == 0 && any != 0ULL) atomicOr(mflag, 1);
  }
}

// ---- shared 128x128 tile GEMM core (C = A * Bt^T), K multiple of 64 --------
__device__ __forceinline__ void gemm_core(const u16* __restrict__ A, const u16* __restrict__ Bt,
                                          int K, u16* As, u16* Bs, int tm0, int tn0,
                                          f32x4 acc[4][4]) {
  const int tid = threadIdx.x;
  const int wv = tid >> 6, ln = tid & 63;
  const int lr = ln & 15, hi = ln >> 4;
  const int wr = wv >> 1, wc = wv & 1;
  const size_t rowbytes = (size_t)K * 2;
  for (int k0 = 0; k0 < K; k0 += 64) {
    __syncthreads();
    const char* Ab = (const char*)A + (size_t)tm0 * rowbytes + (size_t)k0 * 2;
    const char* Bb = (const char*)Bt + (size_t)tn0 * rowbytes + (size_t)k0 * 2;
#pragma unroll
    for (int c = 0; c < 4; ++c) {
      int lin = wv * 4096 + c * 1024 + ln * 16;
      int row = lin >> 7;
      int cb = (lin & 127) ^ ((row & 7) << 4);  // pre-swizzled global source
      gload16(Ab + (size_t)row * rowbytes + cb, (char*)As + wv * 4096 + c * 1024);
      gload16(Bb + (size_t)row * rowbytes + cb, (char*)Bs + wv * 4096 + c * 1024);
    }
    __syncthreads();
#pragma unroll
    for (int ks = 0; ks < 2; ++ks) {
      short8 af[4], bf[4];
#pragma unroll
      for (int m = 0; m < 4; ++m) af[m] = ldfrag(As, wr * 64 + m * 16 + lr, ks * 64 + hi * 16);
#pragma unroll
      for (int n = 0; n < 4; ++n) bf[n] = ldfrag(Bs, wc * 64 + n * 16 + lr, ks * 64 + hi * 16);
#pragma unroll
      for (int m = 0; m < 4; ++m)
#pragma unroll
        for (int n = 0; n < 4; ++n)
          acc[m][n] = __builtin_amdgcn_mfma_f32_16x16x32_bf16(af[m], bf[n], acc[m][n], 0, 0, 0);
    }
  }
}

// ---- QKV projection: z=0 -> q; z=1 -> K frag-major; z=2 -> V^T frag-major --
__global__ __launch_bounds__(256) void qkv_gemm(
    const u16* __restrict__ xq, const u16* __restrict__ xr,
    const u16* __restrict__ wqt, const u16* __restrict__ wkt, const u16* __restrict__ wvt,
    u16* __restrict__ qo, u16* __restrict__ kfr, u16* __restrict__ vfr) {
  __shared__ u16 As[128 * 64];
  __shared__ u16 Bs[128 * 64];
  const int z = blockIdx.z;
  const u16* A  = (z == 0) ? xq : xr;
  const u16* Bt = (z == 0) ? wqt : (z == 1) ? wkt : wvt;
  const int tm0 = blockIdx.x * 128, tn0 = blockIdx.y * 128;
  f32x4 acc[4][4];
#pragma unroll
  for (int m = 0; m < 4; ++m)
#pragma unroll
    for (int n = 0; n < 4; ++n) { f32x4 zz = {0.f, 0.f, 0.f, 0.f}; acc[m][n] = zz; }
  gemm_core(A, Bt, 512, As, Bs, tm0, tn0, acc);

  const int tid = threadIdx.x, wv = tid >> 6, ln = tid & 63, lr = ln & 15, hi = ln >> 4;
  const int wr = wv >> 1, wc = wv & 1;
  const float scale = (z == 0) ? 0.125f * LOG2E : 1.0f;  // fold log2e for exp2 softmax
#pragma unroll
  for (int m = 0; m < 4; ++m) {
#pragma unroll
    for (int n = 0; n < 4; ++n) {
#pragma unroll
      for (int r = 0; r < 4; ++r) {
        int rg = tm0 + wr * 64 + m * 16 + hi * 4 + r;  // global row in [0,8192)
        int cg = tn0 + wc * 64 + n * 16 + lr;          // global col in [0,512)
        int nb = rg >> 12, t = rg & 4095;
        int h = cg >> 6, s = cg & 63;
        int head = nb * 8 + h;
        u16 b = f2bf(acc[m][n][r] * scale);
        if (z == 0) {
          qo[((size_t)head * 4096 + t) * 64 + s] = b;
        } else if (z == 1) {
          int tile = t >> 5, lqk = t & 31;
          int ks = s >> 4, hh = (s >> 3) & 1, j = s & 7;
          kfr[((((size_t)(head * 128 + tile)) * 5 + ks) * 64 + hh * 32 + lqk) * 8 + j] = b;
        } else {
          // V^T frag-major: key from t, s-lane from s (swapped-PV A-operand)
          int tile = t >> 5, key5 = t & 31;
          int c = key5 >> 4, w = key5 & 15;
          int hh2 = (w >> 2) & 1;
          int j2 = (w & 3) + ((w >> 3) << 2);
          int st = s >> 5, lqs = s & 31;
          vfr[((((size_t)(head * 128 + tile)) * 4 + c * 2 + st) * 64 + hh2 * 32 + lqs) * 8 + j2] = b;
        }
      }
    }
  }
}

// ---- flash attention v18: v16 body + cross-wave phase skew (s_sleep probe) -
// grid 256 blocks (xcd-affine, 2 heads/XCD), 512 thr:
// qt = wv&3 (64 q-rows), kg = wv>>2 (2048 keys = 64 tiles of KBLK=32).
__global__ __launch_bounds__(512, 2) void attn18_kernel(
    const u16* __restrict__ q, const char* __restrict__ kfr, const char* __restrict__ vfr,
    u16* __restrict__ ctx, const int* __restrict__ mflag) {
  __shared__ __align__(16) char smem[4 * 32 * 65 * 4];  // 33280B, aliased below
  __shared__ float cl[4][64];
  float (*cmbraw)[32][64] = (float(*)[32][64])smem;   // KSPLIT partial pass
  float (*cmb2)[32][65]   = (float(*)[32][65])smem;   // padded transpose pass
  const int id = blockIdx.x;
  const int xcd = id & 7, slot = id >> 3;
  const int head = xcd * 2 + (slot >> 4);  // 2 heads per XCD
  const int qb = slot & 15;
  const int n = head >> 3, h = head & 7;
  const int tid = threadIdx.x, wv = tid >> 6, ln = tid & 63;
  const int lq = ln & 31, hi = ln >> 5, hi4 = hi * 4;
  const int qt = wv & 3, kg = wv >> 2;
  const int q0 = qb * 256 + qt * 64;
  const bool aug = (*mflag != 0);  // uniform: mask has nonzero entries?

  // Q fragments for two q-sets (rows q0+lq and q0+32+lq); [4]=aug unit col
  short8 qfa[5], qfb[5];
  {
    const char* qp = (const char*)(q + (size_t)head * 4096 * 64) + (size_t)(q0 + lq) * 128 + hi * 16;
#pragma unroll
    for (int ks = 0; ks < 4; ++ks) {
      qfa[ks] = *(const short8*)(qp + ks * 32);
      qfb[ks] = *(const short8*)(qp + 32 * 128 + ks * 32);
    }
    short8 z = {0, 0, 0, 0, 0, 0, 0, 0};
    if (hi == 0) z[0] = (short)0x3F80;  // bf16 1.0 at s=64 (mask aug)
    qfa[4] = z;
    qfb[4] = z;
  }

  // frag-major bases: every load is base + ln*16 (fully coalesced)
  const char* kp = kfr + (size_t)head * 655360 + (size_t)(kg * 64) * 5120 + ln * 16;
  const char* vp = vfr + (size_t)head * 524288 + (size_t)(kg * 64) * 4096 + ln * 16;

  // prologue: first K tile (slot 4 only when aug path active)
  short8 kA[5];
#pragma unroll
  for (int s = 0; s < 4; ++s) kA[s] = *(const short8*)(kp + s * 1024);
  if (aug) kA[4] = *(const short8*)(kp + 4 * 1024);
  kp += 5120;

  // phase-skew probe: desynchronize the two co-resident waves per SIMD
  // (kg=1 waves sleep ~128 cyc once; no barriers in loop -> skew persists)
  if (kg == 1) __builtin_amdgcn_s_sleep(2);

  f32x16 cacc0a = zero16(), cacc1a = zero16();  // s 0..31 / 32..63 (regs), q lanes
  f32x16 cacc0b = zero16(), cacc1b = zero16();
  f32x16 la = zero16(), lb = zero16();  // deferred row-sum accumulators

  for (int it = 0; it < 64; ++it) {
    // V^T frags for current tile (slots c*2+st)
    short8 vt[4];
#pragma unroll
    for (int s = 0; s < 4; ++s) vt[s] = *(const short8*)(vp + s * 1024);
    vp += 4096;

    // ---- QK^T q-set A, then q-set B (independent MFMA chains)
    f32x16 Sa = zero16(), Sb = zero16();
    __builtin_amdgcn_s_setprio(1);
#pragma unroll
    for (int ks = 0; ks < 4; ++ks)
      Sa = __builtin_amdgcn_mfma_f32_32x32x16_bf16(kA[ks], qfa[ks], Sa, 0, 0, 0);
    if (aug) Sa = __builtin_amdgcn_mfma_f32_32x32x16_bf16(kA[4], qfa[4], Sa, 0, 0, 0);
#pragma unroll
    for (int ks = 0; ks < 4; ++ks)
      Sb = __builtin_amdgcn_mfma_f32_32x32x16_bf16(kA[ks], qfb[ks], Sb, 0, 0, 0);
    if (aug) Sb = __builtin_amdgcn_mfma_f32_32x32x16_bf16(kA[4], qfb[4], Sb, 0, 0, 0);
    __builtin_amdgcn_s_setprio(0);

    // ---- prefetch next K tile (hidden under softmax VALU)
    short8 kN[5];
#pragma unroll
    for (int s = 0; s < 4; ++s) kN[s] = *(const short8*)(kp + s * 1024);
    if (aug) kN[4] = *(const short8*)(kp + 4 * 1024);
    kp += 5120;

    // ---- softmax_a (VALU; overlaps tail of QK_b MFMA chain)
    float pa_[16];
#pragma unroll
    for (int r = 0; r < 16; ++r) { pa_[r] = __builtin_amdgcn_exp2f(Sa[r]); la[r] += pa_[r]; }
    short8 pA0, pA1;
    {
      i32x4 f0 = {(int)cvtpk_bf16(pa_[0], pa_[1]), (int)cvtpk_bf16(pa_[2], pa_[3]),
                  (int)cvtpk_bf16(pa_[4], pa_[5]), (int)cvtpk_bf16(pa_[6], pa_[7])};
      i32x4 f1 = {(int)cvtpk_bf16(pa_[8], pa_[9]), (int)cvtpk_bf16(pa_[10], pa_[11]),
                  (int)cvtpk_bf16(pa_[12], pa_[13]), (int)cvtpk_bf16(pa_[14], pa_[15])};
      pA0 = __builtin_bit_cast(short8, f0);
      pA1 = __builtin_bit_cast(short8, f1);
    }

    // ---- PV_a (MFMA; overlaps softmax_b below via scheduler)
    __builtin_amdgcn_s_setprio(1);
    cacc0a = __builtin_amdgcn_mfma_f32_32x32x16_bf16(vt[0], pA0, cacc0a, 0, 0, 0);
    cacc1a = __builtin_amdgcn_mfma_f32_32x32x16_bf16(vt[1], pA0, cacc1a, 0, 0, 0);
    cacc0a = __builtin_amdgcn_mfma_f32_32x32x16_bf16(vt[2], pA1, cacc0a, 0, 0, 0);
    cacc1a = __builtin_amdgcn_mfma_f32_32x32x16_bf16(vt[3], pA1, cacc1a, 0, 0, 0);
    __builtin_amdgcn_s_setprio(0);

    // ---- softmax_b (VALU; overlaps PV_a MFMA chain)
    float pb_[16];
#pragma unroll
    for (int r = 0; r < 16; ++r) { pb_[r] = __builtin_amdgcn_exp2f(Sb[r]); lb[r] += pb_[r]; }
    short8 pB0, pB1;
    {
      i32x4 g0 = {(int)cvtpk_bf16(pb_[0], pb_[1]), (int)cvtpk_bf16(pb_[2], pb_[3]),
                  (int)cvtpk_bf16(pb_[4], pb_[5]), (int)cvtpk_bf16(pb_[6], pb_[7])};
      i32x4 g1 = {(int)cvtpk_bf16(pb_[8], pb_[9]), (int)cvtpk_bf16(pb_[10], pb_[11]),
                  (int)cvtpk_bf16(pb_[12], pb_[13]), (int)cvtpk_bf16(pb_[14], pb_[15])};
      pB0 = __builtin_bit_cast(short8, g0);
      pB1 = __builtin_bit_cast(short8, g1);
    }

    // ---- PV_b
    __builtin_amdgcn_s_setprio(1);
    cacc0b = __builtin_amdgcn_mfma_f32_32x32x16_bf16(vt[0], pB0, cacc0b, 0, 0, 0);
    cacc1b = __builtin_amdgcn_mfma_f32_32x32x16_bf16(vt[1], pB0, cacc1b, 0, 0, 0);
    cacc0b = __builtin_amdgcn_mfma_f32_32x32x16_bf16(vt[2], pB1, cacc0b, 0, 0, 0);
    cacc1b = __builtin_amdgcn_mfma_f32_32x32x16_bf16(vt[3], pB1, cacc1b, 0, 0, 0);
    __builtin_amdgcn_s_setprio(0);

#pragma unroll
    for (int s = 0; s < 4; ++s) kA[s] = kN[s];
    if (aug) kA[4] = kN[4];
  }

  // ---- finalize deferred row-sums (per-lane q -> no bpermute needed)
  float lra, lrb;
  {
    float ta[16], tb[16];
#pragma unroll
    for (int r = 0; r < 16; ++r) { ta[r] = la[r]; tb[r] = lb[r]; }
#pragma unroll
    for (int d = 8; d > 0; d >>= 1)
#pragma unroll
      for (int r = 0; r < d; ++r) { ta[r] += ta[r + d]; tb[r] += tb[r + d]; }
    lra = ta[0] + __shfl_xor(ta[0], 32);
    lrb = tb[0] + __shfl_xor(tb[0], 32);
  }

  // ---- KSPLIT combine + normalize + LDS transpose + coalesced store -------
  auto epilogue = [&](f32x16& c0, f32x16& c1, float lr, int qofs) {
    if (kg == 1) {
#pragma unroll
      for (int r = 0; r < 16; ++r) {
        cmbraw[qt][r][ln] = c0[r];
        cmbraw[qt][r + 16][ln] = c1[r];
      }
      cl[qt][ln] = lr;
    }
    __syncthreads();
    if (kg == 0) {
#pragma unroll
      for (int r = 0; r < 16; ++r) {
        c0[r] += cmbraw[qt][r][ln];
        c1[r] += cmbraw[qt][r + 16][ln];
      }
      lr += cl[qt][ln];
    }
    __syncthreads();  // cmbraw dead; region becomes cmb2
    if (kg == 0) {
      float li = 1.0f / lr;
#pragma unroll
      for (int r = 0; r < 16; ++r) {
        int s0 = (r & 3) + ((r >> 2) << 3) + hi4;  // s within 32-half
        cmb2[qt][lq][s0] = c0[r] * li;
        cmb2[qt][lq][32 + s0] = c1[r] * li;
      }
    }
    __syncthreads();
    {
      u16* cpx = ctx + (size_t)(n * 4096 + qb * 256 + qt * 64 + qofs) * 512 + h * 64;
#pragma unroll
      for (int rr = 0; rr < 16; ++rr) {
        int qq = kg * 16 + rr;
        cpx[(size_t)qq * 512 + ln] = f2bf(cmb2[qt][qq][ln]);
      }
    }
    __syncthreads();  // before region is reused
  };
  epilogue(cacc0a, cacc1a, lra, 0);
  epilogue(cacc0b, cacc1b, lrb, 32);
}

// ---- output projection: 128x64 tiles (2 blocks/CU), out = ctx * WoT^T ------
__global__ __launch_bounds__(256) void out_gemm(
    const u16* __restrict__ ctx, const u16* __restrict__ wot, float* __restrict__ out) {
  __shared__ u16 As[128 * 64];  // 16KB
  __shared__ u16 Bs[64 * 64];   // 8KB
  const int tm0 = blockIdx.x * 128, tn0 = blockIdx.y * 64;
  const int tid = threadIdx.x, wv = tid >> 6, ln = tid & 63;
  const int lr = ln & 15, hi = ln >> 4;
  f32x4 acc[2][4];
#pragma unroll
  for (int m = 0; m < 2; ++m)
#pragma unroll
    for (int n = 0; n < 4; ++n) { f32x4 zz = {0.f, 0.f, 0.f, 0.f}; acc[m][n] = zz; }

  const size_t rowbytes = 1024;  // K=512 * 2B
  for (int k0 = 0; k0 < 512; k0 += 64) {
    __syncthreads();
    const char* Ab = (const char*)ctx + (size_t)tm0 * rowbytes + (size_t)k0 * 2;
    const char* Bb = (const char*)wot + (size_t)tn0 * rowbytes + (size_t)k0 * 2;
#pragma unroll
    for (int c = 0; c < 4; ++c) {
      int lin = wv * 4096 + c * 1024 + ln * 16;
      int row = lin >> 7;
      int cb = (lin & 127) ^ ((row & 7) << 4);
      gload16(Ab + (size_t)row * rowbytes + cb, (char*)As + wv * 4096 + c * 1024);
    }
#pragma unroll
    for (int c = 0; c < 2; ++c) {
      int lin = wv * 2048 + c * 1024 + ln * 16;
      int row = lin >> 7;
      int cb = (lin & 127) ^ ((row & 7) << 4);
      gload16(Bb + (size_t)row * rowbytes + cb, (char*)Bs + wv * 2048 + c * 1024);
    }
    __syncthreads();
#pragma unroll
    for (int ks = 0; ks < 2; ++ks) {
      short8 af[2], bf[4];
#pragma unroll
      for (int m = 0; m < 2; ++m) af[m] = ldfrag(As, wv * 32 + m * 16 + lr, ks * 64 + hi * 16);
#pragma unroll
      for (int n = 0; n < 4; ++n) bf[n] = ldfrag(Bs, n * 16 + lr, ks * 64 + hi * 16);
#pragma unroll
      for (int m = 0; m < 2; ++m)
#pragma unroll
        for (int n = 0; n < 4; ++n)
          acc[m][n] = __builtin_amdgcn_mfma_f32_16x16x32_bf16(af[m], bf[n], acc[m][n], 0, 0, 0);
    }
  }
#pragma unroll
  for (int m = 0; m < 2; ++m)
#pragma unroll
    for (int n = 0; n < 4; ++n)
#pragma unroll
      for (int r = 0; r < 4; ++r) {
        int rg = tm0 + wv * 32 + m * 16 + hi * 4 + r;
        int cg = tn0 + n * 16 + lr;
        out[(size_t)rg * 512 + cg] = acc[m][n][r];
      }
}

// ---- launch ----------------------------------------------------------------
extern "C" void kernel_launch(void* const* d_in, const int* in_sizes, int n_in,
                              void* d_out, int out_size, void* d_ws, size_t ws_size,
                              hipStream_t stream) {
  (void)in_sizes; (void)n_in; (void)out_size; (void)ws_size;
  const float* qin  = (const float*)d_in[0];
  const float* rin  = (const float*)d_in[1];
  const float* mask = (const float*)d_in[2];
  const float* wq   = (const float*)d_in[3];
  const float* wk   = (const float*)d_in[4];
  const float* wv   = (const float*)d_in[5];
  const float* wo   = (const float*)d_in[6];

  char* ws = (char*)d_ws;
  u16* xq   = (u16*)(ws + 0);         // [8192][512] bf16 (region reused by ctx)
  u16* ctx  = (u16*)(ws + 0);         // [8192][512] bf16 (written after xq dead)
  u16* xr   = (u16*)(ws + 8388608);   // [8192][512]
  u16* wqt  = (u16*)(ws + 16777216);  // [512][512] transposed
  u16* wkt  = (u16*)(ws + 17301504);
  u16* wvt  = (u16*)(ws + 17825792);
  u16* wot  = (u16*)(ws + 18350080);
  u16* qo   = (u16*)(ws + 18874368);  // [16][4096][64]
  u16* kfr  = (u16*)(ws + 27262976);  // frag-major K+mask: 16*128*5*64*8 u16 = 10.5MB
  u16* vfr  = (u16*)(ws + 37748736);  // frag-major V^T:    16*128*4*64*8 u16 = 8MB
  int* mflag = (int*)(ws + 46137344); // mask-nonzero flag

  hipMemsetAsync(mflag, 0, 4, stream);
  prep_kernel<<<2048, 256, 0, stream>>>((const float4*)qin, (const float4*)rin, mask,
                                        wq, wk, wv, wo, xq, xr, wqt, wkt, wvt, wot,
                                        kfr, mflag);
  qkv_gemm<<<dim3(64, 4, 3), 256, 0, stream>>>(xq, xr, wqt, wkt, wvt, qo, kfr, vfr);
  attn18_kernel<<<256, 512, 0, stream>>>(qo, (const char*)kfr, (const char*)vfr, ctx, mflag);
  out_gemm<<<dim3(64, 8), 256, 0, stream>>>(ctx, wot, (float*)d_out);
}